// Round 18
// baseline (48.764 us; speedup 1.0000x reference)
//
#include <hip/hip_runtime.h>
#include <cstddef>

#define B_ 2
#define C_ 32
#define CP 33
#define W_ 256
#define H_ 256
#define X_ 512
#define Y_ 512

typedef __bf16 bf16x8 __attribute__((ext_vector_type(8)));
typedef __bf16 bf16x4 __attribute__((ext_vector_type(4)));
typedef float  f32x4  __attribute__((ext_vector_type(4)));

#define AS1 __attribute__((address_space(1)))
#define AS3 __attribute__((address_space(3)))

__device__ __forceinline__ void gload16_lds(const void* g, void* l) {
    // async global->LDS, 16B/lane, LDS dest = wave-uniform base + lane*16
    __builtin_amdgcn_global_load_lds((const AS1 void*)g, (AS3 void*)l, 16, 0, 0);
}

// ws layout (bf16), ALL frag-linear (round-14/16/17 lesson: every staging
// instruction must read 1KB contiguous; 16-row scatter = 16 transactions
// per instr -> TA-pipe serialization was THE stall):
//   wlonF [B][xt8][kt8][nf4][lane64][8]      262144
//   wlatF [B][yt8][kt8][bf4][lane64][8]      262144
//   wt33F [p=B*CP][wt2][kt8][rf8][lane64][8] 4325376  (ch0=density)
//   U_F   [p=B*CP][yt8][kt8][rq4][lane64][8] 4325376

// ---------------- prep: bf16 tables, frag-linear ----------------
__global__ __launch_bounds__(256) void prep_kernel(
    const float* __restrict__ xin_lon, const float* __restrict__ xin_lat,
    const float* __restrict__ xout_lon, const float* __restrict__ xout_lat,
    const float* __restrict__ init_ls, const float* __restrict__ wt,
    __bf16* __restrict__ wlonF, __bf16* __restrict__ wlatF,
    __bf16* __restrict__ wt33F)
{
    const int NLONC = 32768;              // B*X*W/8 chunks
    const int NLATC = 32768;              // B*Y*H/8 chunks
    int t = blockIdx.x * 256 + threadIdx.x;
    float ls = init_ls[0];
    float cc = -0.5f / (ls * ls);
    if (t < NLONC) {
        // (b, xt, kt, nf, lane): x = xt*64+nf*16+(lane&15), k0 = kt*32+(lane>>4)*8
        int lane = t & 63, nf = (t >> 6) & 3, kt = (t >> 8) & 7;
        int xt = (t >> 11) & 7, b = t >> 14;
        int x  = xt * 64 + nf * 16 + (lane & 15);
        int k0 = kt * 32 + (lane >> 4) * 8;
        float xo = xout_lon[b * X_ + x];
        bf16x8 v;
#pragma unroll
        for (int e = 0; e < 8; ++e) {
            float d = xin_lon[b * W_ + k0 + e] - xo;
            v[e] = (__bf16)__expf(cc * d * d);
        }
        *(bf16x8*)&wlonF[(size_t)t * 8] = v;
    } else if (t < NLONC + NLATC) {
        int c = t - NLONC;
        // (b, yt, kt, bf, lane): y = yt*64+bf*16+(lane&15), h0 = kt*32+(lane>>4)*8
        int lane = c & 63, bfr = (c >> 6) & 3, kt = (c >> 8) & 7;
        int yt = (c >> 11) & 7, b = c >> 14;
        int y  = yt * 64 + bfr * 16 + (lane & 15);
        int h0 = kt * 32 + (lane >> 4) * 8;
        float yo = xout_lat[b * Y_ + y];
        bf16x8 v;
#pragma unroll
        for (int e = 0; e < 8; ++e) {
            float d = xin_lat[b * H_ + h0 + e] - yo;
            v[e] = (__bf16)__expf(cc * d * d);
        }
        *(bf16x8*)&wlatF[(size_t)c * 8] = v;
    } else {
        int j = t - (NLONC + NLATC);      // wt33F chunk, 540672 total
        if (j >= 540672) return;
        int p  = j >> 13;                 // 8192 chunks per panel
        int c2 = j & 8191;
        int wtile = c2 >> 12, kt = (c2 >> 9) & 7, rf = (c2 >> 6) & 7, lane = c2 & 63;
        int w  = wtile * 128 + rf * 16 + (lane & 15);
        int h0 = kt * 32 + (lane >> 4) * 8;
        int b  = p / CP, ch = p - b * CP;
        bf16x8 ov;
        if (ch == 0) {
            const float* src = &wt[((size_t)b * C_) * (W_ * H_) + (size_t)w * H_ + h0];
            float4 a0 = *(const float4*)src;
            float4 a1 = *(const float4*)(src + 4);
            float vv[8] = {a0.x, a0.y, a0.z, a0.w, a1.x, a1.y, a1.z, a1.w};
#pragma unroll
            for (int e = 0; e < 8; ++e)
                ov[e] = (__bf16)((vv[e] != vv[e]) ? 0.f : 1.f);
        } else {
            const float* src = &wt[((size_t)b * C_ + (ch - 1)) * (W_ * H_)
                                   + (size_t)w * H_ + h0];
            float4 a0 = *(const float4*)src;
            float4 a1 = *(const float4*)(src + 4);
            float vv[8] = {a0.x, a0.y, a0.z, a0.w, a1.x, a1.y, a1.z, a1.w};
#pragma unroll
            for (int e = 0; e < 8; ++e)
                ov[e] = (__bf16)((vv[e] != vv[e]) ? 0.f : vv[e]);
        }
        *(bf16x8*)&wt33F[(size_t)j * 8] = ov;
    }
}

// ---------------- stage 1: U_F = frag-linear (wt33 x wlat^T)^T ----------
// 128(w) x 64(y) x K256, 1056 blocks, 2-slot ring, counted vmcnt(3).
// ALL staging 1KB-contiguous. Epilogue: LDS transpose -> 1KB-contiguous
// U_F chunk writes.
__global__ __launch_bounds__(256, 4) void gemm_u(
    const __bf16* __restrict__ wt33F, const __bf16* __restrict__ wlatF,
    __bf16* __restrict__ U_F)
{
    __shared__ union SM {
        struct { __bf16 A[2][4096]; __bf16 Bt[2][2048]; } t;  // 24 KB
        __bf16 th[8704];     // 64 x 136 (bf16 transpose, padded)
    } sm;

    const int t    = threadIdx.x;
    const int lane = t & 63;
    const int wave = t >> 6;
    const int wm   = wave >> 1, wn = wave & 1;
    const int lrow = lane & 15, lkg = lane >> 4;

    // bijective chunked XCD swizzle (1056 % 8 == 0)
    const int xcd = blockIdx.x & 7, k = blockIdx.x >> 3;  // k: 0..131
    const int m   = xcd * 132 + k;
    const int p   = m >> 4, tile = m & 15;
    const int mtile = tile >> 3, ntile = tile & 7;        // 2(w) x 8(y)
    const int bb = (p >= CP) ? 1 : 0;
    const __bf16* Abase = wt33F + ((size_t)(p * 2 + mtile)) * 32768;
    const __bf16* Bbase = wlatF + ((size_t)(bb * 8 + ntile)) * 16384;

    auto stage = [&](int buf, int kt) {
#pragma unroll
        for (int j = 0; j < 2; ++j) {
            int rf = j * 4 + wave;                         // A frags 0..7
            gload16_lds((const void*)(Abase + (size_t)(kt * 8 + rf) * 512 + lane * 8),
                        (void*)&sm.t.A[buf][rf * 512]);
        }
        gload16_lds((const void*)(Bbase + (size_t)(kt * 4 + wave) * 512 + lane * 8),
                    (void*)&sm.t.Bt[buf][wave * 512]);     // B frags 0..3
    };

    f32x4 acc[4][2] = {};
    stage(0, 0);
#pragma unroll
    for (int kt = 0; kt < 8; ++kt) {
        const int buf = kt & 1;
        if (kt < 7) {
            stage(buf ^ 1, kt + 1);
            asm volatile("s_waitcnt vmcnt(3)" ::: "memory");  // cur tile landed
        } else {
            asm volatile("s_waitcnt vmcnt(0)" ::: "memory");
        }
        __builtin_amdgcn_s_barrier();
        bf16x8 af[4], bf[2];
#pragma unroll
        for (int mt = 0; mt < 4; ++mt)
            af[mt] = *(const bf16x8*)&sm.t.A[buf][((wm * 4 + mt) * 64 + lane) * 8];
#pragma unroll
        for (int nt = 0; nt < 2; ++nt)
            bf[nt] = *(const bf16x8*)&sm.t.Bt[buf][((wn * 2 + nt) * 64 + lane) * 8];
#pragma unroll
        for (int mt = 0; mt < 4; ++mt)
#pragma unroll
            for (int nt = 0; nt < 2; ++nt)
                acc[mt][nt] = __builtin_amdgcn_mfma_f32_16x16x32_bf16(
                    af[mt], bf[nt], acc[mt][nt], 0, 0, 0);
        __builtin_amdgcn_sched_barrier(0);
        __builtin_amdgcn_s_barrier();
    }

    // LDS transpose tile [64y][128w] then write frag-linear U_F chunks
#pragma unroll
    for (int mt = 0; mt < 4; ++mt)
#pragma unroll
        for (int nt = 0; nt < 2; ++nt) {
            int yloc = wn * 32 + nt * 16 + lrow;
            int wloc = wm * 64 + mt * 16 + lkg * 4;
            f32x4 c = acc[mt][nt];
            bf16x4 v4;
            v4[0] = (__bf16)c[0]; v4[1] = (__bf16)c[1];
            v4[2] = (__bf16)c[2]; v4[3] = (__bf16)c[3];
            *(bf16x4*)&sm.th[yloc * 136 + wloc] = v4;
        }
    __syncthreads();
    // U_F[p][yt=ntile][ktg=mtile*4+ktl][rq][lane][8]
    __bf16* up = U_F + (size_t)p * 131072 + (size_t)ntile * 16384
                 + (size_t)mtile * 4 * 2048;
#pragma unroll
    for (int it = 0; it < 4; ++it) {
        int c2 = it * 256 + t;
        int ktl = c2 >> 8, rq = (c2 >> 6) & 3, ln = c2 & 63;
        int yloc = rq * 16 + (ln & 15);
        int w8   = ktl * 4 + (ln >> 4);
        bf16x8 v = *(const bf16x8*)&sm.th[yloc * 136 + w8 * 8];
        *(bf16x8*)&up[(size_t)(ktl * 4 + rq) * 512 + ln * 8] = v;
    }
}

// ---------------- stage 2 fused: 16-phase continuous, single round ----
// 512 blocks (ALL co-resident), each runs TWO yt segments back-to-back in
// one continuous 16-phase k-loop: one prologue, one drain, epilogues after
// the loop (stores never pollute in-loop vmcnt). Round-17 lesson: removed
// the mid-phase lgkmcnt(0)+sched_barrier pin (m141: order-pinning defeats
// the compiler's fine-grained scheduling); hoist hazard is covered by the
// vmcnt asm's memory clobber at phase start.
__global__ __launch_bounds__(256, 2) void stage2_fused(
    const __bf16* __restrict__ wlonF, const __bf16* __restrict__ U_F,
    float* __restrict__ out)
{
    __shared__ __bf16 Ast[2][12288];    // 48 KB: 2 slots x (20 A + 4 B frags)

    const int t = threadIdx.x, lane = t & 63, wave = t >> 6;
    const int lrow = lane & 15, lkg = lane >> 4;
    const int wm = wave >> 1, wn = wave & 1;

    const int bid  = blockIdx.x;                   // 0..511
    const int xcd  = bid & 7, r = bid >> 3;        // r: 0..63
    const int combo = (r >> 5) * 8 + xcd;          // 2 combos per XCD (b pair)
    const int b    = combo >> 3, g = combo & 7;
    const int tile = r & 31;
    const int ytp  = tile >> 3, xt = tile & 7;     // ytp 0..3, xt 0..7
    const int x0   = xt * 64;

    const __bf16* lonF = wlonF + (size_t)(b * 8 + xt) * 16384;   // [kt][nf][lane][8]
    const __bf16* Ub0  = U_F + (size_t)(b * CP) * 131072 + (size_t)(ytp * 2) * 16384;
    const __bf16* Ub1  = Ub0 + 16384;

    // staging: 24 frags/phase; jf<20 -> A (ch block jj=jf>>2, rq=jf&3),
    // jf>=20 -> B (nf=jf-20). src = frag base + lane*16B: 1KB contiguous.
    auto stage = [&](int slot, int ph) {
        const __bf16* ub = (ph < 8) ? Ub0 : Ub1;
        const int kt = ph & 7;
#pragma unroll
        for (int i = 0; i < 6; ++i) {
            const int jf = wave * 6 + i;
            const __bf16* src;
            if (jf < 20) {
                const int jj = jf >> 2;
                const int ch = (jj == 0) ? 0 : (g * 4 + jj);
                src = ub + (size_t)ch * 131072
                      + (size_t)(kt * 4 + (jf & 3)) * 512 + lane * 8;
            } else {
                src = lonF + (size_t)(kt * 4 + (jf - 20)) * 512 + lane * 8;
            }
            gload16_lds((const void*)src, (void*)&Ast[slot][jf * 512]);
        }
    };

    f32x4 acc[2][5][2][2] = {};     // [seg][ch][mt][nt]

    stage(0, 0);
#pragma unroll
    for (int ph = 0; ph < 16; ++ph) {
        const int slot = ph & 1;
        const int seg  = ph >> 3;
        if (ph < 15) {
            stage(slot ^ 1, ph + 1);
            asm volatile("s_waitcnt vmcnt(6)" ::: "memory");   // phase ph landed
        } else {
            asm volatile("s_waitcnt vmcnt(0)" ::: "memory");
        }
        __builtin_amdgcn_s_barrier();
        bf16x8 af[5][2], bfv[2];
#pragma unroll
        for (int j = 0; j < 5; ++j)
#pragma unroll
            for (int mt = 0; mt < 2; ++mt)
                af[j][mt] = *(const bf16x8*)
                    &Ast[slot][((j * 4 + wm * 2 + mt) * 64 + lane) * 8];
#pragma unroll
        for (int nt = 0; nt < 2; ++nt)
            bfv[nt] = *(const bf16x8*)
                &Ast[slot][((20 + wn * 2 + nt) * 64 + lane) * 8];
        // no lgkm/sched pin here: compiler fine-schedules reads vs MFMAs
#pragma unroll
        for (int j = 0; j < 5; ++j)
#pragma unroll
            for (int mt = 0; mt < 2; ++mt)
#pragma unroll
                for (int nt = 0; nt < 2; ++nt)
                    acc[seg][j][mt][nt] = __builtin_amdgcn_mfma_f32_16x16x32_bf16(
                        af[j][mt], bfv[nt], acc[seg][j][mt][nt], 0, 0, 0);
        __builtin_amdgcn_sched_barrier(0);   // WAR: reads done before barrier
        __builtin_amdgcn_s_barrier();        // slot safe to overwrite
    }

    // ---- epilogues: rec from density acc, divide, store (both segments) ----
#pragma unroll
    for (int seg = 0; seg < 2; ++seg) {
        const int y0 = ytp * 128 + seg * 64;
        f32x4 rec[2][2];
#pragma unroll
        for (int mt = 0; mt < 2; ++mt)
#pragma unroll
            for (int nt = 0; nt < 2; ++nt) {
                f32x4 c = acc[seg][0][mt][nt], q2;
#pragma unroll
                for (int rr = 0; rr < 4; ++rr)
                    q2[rr] = 1.0f / fminf(fmaxf(c[rr], 1e-6f), 1e5f);
                rec[mt][nt] = q2;
            }
        if (g == 0) {
            float* outc = out + (size_t)(b * CP) * (X_ * Y_);
#pragma unroll
            for (int mt = 0; mt < 2; ++mt)
#pragma unroll
                for (int nt = 0; nt < 2; ++nt) {
                    int xg = x0 + (wn * 2 + nt) * 16 + lrow;
                    int yg = y0 + (wm * 2 + mt) * 16 + lkg * 4;
                    *(f32x4*)&outc[(size_t)xg * Y_ + yg] = acc[seg][0][mt][nt];
                }
        }
#pragma unroll
        for (int j = 1; j < 5; ++j) {
            float* outc = out + (size_t)(b * CP + g * 4 + j) * (size_t)(X_ * Y_);
#pragma unroll
            for (int mt = 0; mt < 2; ++mt)
#pragma unroll
                for (int nt = 0; nt < 2; ++nt) {
                    int xg = x0 + (wn * 2 + nt) * 16 + lrow;
                    int yg = y0 + (wm * 2 + mt) * 16 + lkg * 4;
                    f32x4 v = acc[seg][j][mt][nt] * rec[mt][nt];
                    *(f32x4*)&outc[(size_t)xg * Y_ + yg] = v;
                }
        }
    }
}

extern "C" void kernel_launch(void* const* d_in, const int* in_sizes, int n_in,
                              void* d_out, int out_size, void* d_ws, size_t ws_size,
                              hipStream_t stream)
{
    const float* xin_lon  = (const float*)d_in[0];
    const float* xin_lat  = (const float*)d_in[1];
    const float* wt       = (const float*)d_in[2];
    const float* xout_lon = (const float*)d_in[3];
    const float* xout_lat = (const float*)d_in[4];
    const float* init_ls  = (const float*)d_in[5];
    float* out = (float*)d_out;

    __bf16* wlonF = (__bf16*)d_ws;
    __bf16* wlatF = wlonF + (size_t)B_ * X_ * W_;
    __bf16* wt33F = wlatF + (size_t)B_ * Y_ * H_;
    __bf16* U_F   = wt33F + (size_t)B_ * CP * W_ * H_;

    // 32768 (wlonF) + 32768 (wlatF) + 540672 (wt33F) = 606208 thr = 2368 blk
    prep_kernel<<<2368, 256, 0, stream>>>(xin_lon, xin_lat, xout_lon, xout_lat,
                                          init_ls, wt, wlonF, wlatF, wt33F);
    gemm_u<<<1056, 256, 0, stream>>>(wt33F, wlatF, U_F);
    stage2_fused<<<512, 256, 0, stream>>>(wlonF, U_F, out);
}

// Round 19
// 45.909 us; speedup vs baseline: 1.0622x; 1.0622x over previous
//
#include <hip/hip_runtime.h>
#include <cstddef>

#define B_ 2
#define C_ 32
#define CP 33
#define W_ 256
#define H_ 256
#define X_ 512
#define Y_ 512

typedef __bf16 bf16x8 __attribute__((ext_vector_type(8)));
typedef __bf16 bf16x4 __attribute__((ext_vector_type(4)));
typedef float  f32x4  __attribute__((ext_vector_type(4)));

#define AS1 __attribute__((address_space(1)))
#define AS3 __attribute__((address_space(3)))

__device__ __forceinline__ void gload16_lds(const void* g, void* l) {
    // async global->LDS, 16B/lane, LDS dest = wave-uniform base + lane*16
    __builtin_amdgcn_global_load_lds((const AS1 void*)g, (AS3 void*)l, 16, 0, 0);
}

// ws layout (bf16), ALL frag-linear (rounds 14/16/17: every global access
// -- load OR store, staging OR prep -- must be ~1KB contiguous per wave
// instruction; 16-row scatter = 16 transactions/instr = TA serialization):
//   wlonF [B][xt8][kt8][nf4][lane64][8]      262144
//   wlatF [B][yt8][kt8][bf4][lane64][8]      262144
//   wt33F [p=B*CP][wt2][kt8][rf8][lane64][8] 4325376  (ch0=density)
//   U_F   [p=B*CP][yt8][kt8][rq4][lane64][8] 4325376

// ---------------- prep: LDS-tiled, coalesced reads AND writes ----------
// blocks 0..527: one [64w x 128h] tile of one panel p (66 panels x 8 tiles).
//   reads wt rows 512B-contiguous, converts, LDS transpose-gather, writes
//   16 frag chunks 1KB-contiguous. (round-18 lesson: prep's old per-lane
//   fragment mapping was a 16-row scatter on the 17MB wt read.)
// blocks 528..783: wlonF / wlatF chunks (tiny trig tables).
__global__ __launch_bounds__(256) void prep_kernel(
    const float* __restrict__ xin_lon, const float* __restrict__ xin_lat,
    const float* __restrict__ xout_lon, const float* __restrict__ xout_lat,
    const float* __restrict__ init_ls, const float* __restrict__ wt,
    __bf16* __restrict__ wlonF, __bf16* __restrict__ wlatF,
    __bf16* __restrict__ wt33F)
{
    __shared__ __bf16 tile[64 * 130];   // row stride 130 bf16 (260B, ~2-way)

    const int t = threadIdx.x;
    const int bid = blockIdx.x;
    float ls = init_ls[0];
    float cc = -0.5f / (ls * ls);

    if (bid < 528) {
        const int p  = bid >> 3, tl = bid & 7;
        const int wq = tl >> 1, hq = tl & 1;        // w-64-tile, h-128-tile
        const int b  = p / CP, ch = p - b * CP;
        const float* src = (ch == 0)
            ? wt + ((size_t)b * C_) * (W_ * H_)
            : wt + ((size_t)b * C_ + (ch - 1)) * (W_ * H_);
        const int rowt = t >> 5, hl = (t & 31) * 4;
#pragma unroll
        for (int i = 0; i < 8; ++i) {
            int rl = i * 8 + rowt;                  // 0..63
            const float* sp = src + (size_t)(wq * 64 + rl) * H_ + hq * 128 + hl;
            float4 v = *(const float4*)sp;
            bf16x4 ov;
            if (ch == 0) {
                ov[0] = (__bf16)((v.x != v.x) ? 0.f : 1.f);
                ov[1] = (__bf16)((v.y != v.y) ? 0.f : 1.f);
                ov[2] = (__bf16)((v.z != v.z) ? 0.f : 1.f);
                ov[3] = (__bf16)((v.w != v.w) ? 0.f : 1.f);
            } else {
                ov[0] = (__bf16)((v.x != v.x) ? 0.f : v.x);
                ov[1] = (__bf16)((v.y != v.y) ? 0.f : v.y);
                ov[2] = (__bf16)((v.z != v.z) ? 0.f : v.z);
                ov[3] = (__bf16)((v.w != v.w) ? 0.f : v.w);
            }
            *(bf16x4*)&tile[rl * 130 + hl] = ov;
        }
        __syncthreads();
        // emit 16 frag chunks: chunk ci -> kt_l=ci>>2, rf_l=ci&3;
        // lane: w_loc=rf_l*16+(lane&15), h_loc=kt_l*32+(lane>>4)*8
        const int lane = t & 63, wave = t >> 6;
        __bf16* pb = wt33F + (size_t)p * 65536 + (size_t)(wq >> 1) * 32768;
        const int rfg0 = (wq & 1) * 4, ktg0 = hq * 4;
#pragma unroll
        for (int it = 0; it < 4; ++it) {
            int ci   = it * 4 + wave;
            int kt_l = ci >> 2, rf_l = ci & 3;
            int wl = rf_l * 16 + (lane & 15);
            int hl2 = kt_l * 32 + (lane >> 4) * 8;
            bf16x8 v = *(const bf16x8*)&tile[wl * 130 + hl2];
            *(bf16x8*)&pb[(size_t)((ktg0 + kt_l) * 8 + rfg0 + rf_l) * 512
                          + lane * 8] = v;
        }
    } else {
        int j = (bid - 528) * 256 + t;              // 0..65535
        if (j < 32768) {
            // wlonF chunk: x = xt*64+nf*16+(lane&15), k0 = kt*32+(lane>>4)*8
            int lane = j & 63, nf = (j >> 6) & 3, kt = (j >> 8) & 7;
            int xt = (j >> 11) & 7, b = j >> 14;
            int x  = xt * 64 + nf * 16 + (lane & 15);
            int k0 = kt * 32 + (lane >> 4) * 8;
            float xo = xout_lon[b * X_ + x];
            bf16x8 v;
#pragma unroll
            for (int e = 0; e < 8; ++e) {
                float d = xin_lon[b * W_ + k0 + e] - xo;
                v[e] = (__bf16)__expf(cc * d * d);
            }
            *(bf16x8*)&wlonF[(size_t)j * 8] = v;
        } else {
            int c = j - 32768;
            int lane = c & 63, bfr = (c >> 6) & 3, kt = (c >> 8) & 7;
            int yt = (c >> 11) & 7, b = c >> 14;
            int y  = yt * 64 + bfr * 16 + (lane & 15);
            int h0 = kt * 32 + (lane >> 4) * 8;
            float yo = xout_lat[b * Y_ + y];
            bf16x8 v;
#pragma unroll
            for (int e = 0; e < 8; ++e) {
                float d = xin_lat[b * H_ + h0 + e] - yo;
                v[e] = (__bf16)__expf(cc * d * d);
            }
            *(bf16x8*)&wlatF[(size_t)c * 8] = v;
        }
    }
}

// ---------------- stage 1: U_F = frag-linear (wt33 x wlat^T)^T ----------
// 128(w) x 64(y) x K256, 1056 blocks, 2-slot ring, counted vmcnt(3).
// ALL staging 1KB-contiguous. Epilogue: LDS transpose -> 1KB-contiguous
// U_F chunk writes.
__global__ __launch_bounds__(256, 4) void gemm_u(
    const __bf16* __restrict__ wt33F, const __bf16* __restrict__ wlatF,
    __bf16* __restrict__ U_F)
{
    __shared__ union SM {
        struct { __bf16 A[2][4096]; __bf16 Bt[2][2048]; } t;  // 24 KB
        __bf16 th[8704];     // 64 x 136 (bf16 transpose, padded)
    } sm;

    const int t    = threadIdx.x;
    const int lane = t & 63;
    const int wave = t >> 6;
    const int wm   = wave >> 1, wn = wave & 1;
    const int lrow = lane & 15, lkg = lane >> 4;

    // bijective chunked XCD swizzle (1056 % 8 == 0)
    const int xcd = blockIdx.x & 7, k = blockIdx.x >> 3;  // k: 0..131
    const int m   = xcd * 132 + k;
    const int p   = m >> 4, tile = m & 15;
    const int mtile = tile >> 3, ntile = tile & 7;        // 2(w) x 8(y)
    const int bb = (p >= CP) ? 1 : 0;
    const __bf16* Abase = wt33F + ((size_t)(p * 2 + mtile)) * 32768;
    const __bf16* Bbase = wlatF + ((size_t)(bb * 8 + ntile)) * 16384;

    auto stage = [&](int buf, int kt) {
#pragma unroll
        for (int j = 0; j < 2; ++j) {
            int rf = j * 4 + wave;                         // A frags 0..7
            gload16_lds((const void*)(Abase + (size_t)(kt * 8 + rf) * 512 + lane * 8),
                        (void*)&sm.t.A[buf][rf * 512]);
        }
        gload16_lds((const void*)(Bbase + (size_t)(kt * 4 + wave) * 512 + lane * 8),
                    (void*)&sm.t.Bt[buf][wave * 512]);     // B frags 0..3
    };

    f32x4 acc[4][2] = {};
    stage(0, 0);
#pragma unroll
    for (int kt = 0; kt < 8; ++kt) {
        const int buf = kt & 1;
        if (kt < 7) {
            stage(buf ^ 1, kt + 1);
            asm volatile("s_waitcnt vmcnt(3)" ::: "memory");  // cur tile landed
        } else {
            asm volatile("s_waitcnt vmcnt(0)" ::: "memory");
        }
        __builtin_amdgcn_s_barrier();
        bf16x8 af[4], bf[2];
#pragma unroll
        for (int mt = 0; mt < 4; ++mt)
            af[mt] = *(const bf16x8*)&sm.t.A[buf][((wm * 4 + mt) * 64 + lane) * 8];
#pragma unroll
        for (int nt = 0; nt < 2; ++nt)
            bf[nt] = *(const bf16x8*)&sm.t.Bt[buf][((wn * 2 + nt) * 64 + lane) * 8];
#pragma unroll
        for (int mt = 0; mt < 4; ++mt)
#pragma unroll
            for (int nt = 0; nt < 2; ++nt)
                acc[mt][nt] = __builtin_amdgcn_mfma_f32_16x16x32_bf16(
                    af[mt], bf[nt], acc[mt][nt], 0, 0, 0);
        __builtin_amdgcn_sched_barrier(0);
        __builtin_amdgcn_s_barrier();
    }

    // LDS transpose tile [64y][128w] then write frag-linear U_F chunks
#pragma unroll
    for (int mt = 0; mt < 4; ++mt)
#pragma unroll
        for (int nt = 0; nt < 2; ++nt) {
            int yloc = wn * 32 + nt * 16 + lrow;
            int wloc = wm * 64 + mt * 16 + lkg * 4;
            f32x4 c = acc[mt][nt];
            bf16x4 v4;
            v4[0] = (__bf16)c[0]; v4[1] = (__bf16)c[1];
            v4[2] = (__bf16)c[2]; v4[3] = (__bf16)c[3];
            *(bf16x4*)&sm.th[yloc * 136 + wloc] = v4;
        }
    __syncthreads();
    // U_F[p][yt=ntile][ktg=mtile*4+ktl][rq][lane][8]
    __bf16* up = U_F + (size_t)p * 131072 + (size_t)ntile * 16384
                 + (size_t)mtile * 4 * 2048;
#pragma unroll
    for (int it = 0; it < 4; ++it) {
        int c2 = it * 256 + t;
        int ktl = c2 >> 8, rq = (c2 >> 6) & 3, ln = c2 & 63;
        int yloc = rq * 16 + (ln & 15);
        int w8   = ktl * 4 + (ln >> 4);
        bf16x8 v = *(const bf16x8*)&sm.th[yloc * 136 + w8 * 8];
        *(bf16x8*)&up[(size_t)(ktl * 4 + rq) * 512 + ln * 8] = v;
    }
}

// ---------------- stage 2 fused (round-16/17 proven config) ----------
// (b, channel-group) pinned per XCD; all 5 channels per k-phase (8 phases,
// 20 MFMA each); every staging instruction reads 1KB contiguous.
__global__ __launch_bounds__(256, 2) void stage2_fused(
    const __bf16* __restrict__ wlonF, const __bf16* __restrict__ U_F,
    float* __restrict__ out)
{
    __shared__ __bf16 Ast[2][12288];    // 48 KB: 2 slots x (20 A + 4 B frags)

    const int t = threadIdx.x, lane = t & 63, wave = t >> 6;
    const int lrow = lane & 15, lkg = lane >> 4;
    const int wm = wave >> 1, wn = wave & 1;

    const int bid  = blockIdx.x;
    const int xcd  = bid & 7, q = bid >> 3;        // q: 0..127
    const int combo = (q >> 6) * 8 + xcd;          // 0..15: (b,g) per XCD
    const int b    = combo >> 3, g = combo & 7;
    const int tile = q & 63;
    const int yt   = tile >> 3, xt = tile & 7;
    const int x0   = xt * 64, y0 = yt * 64;

    const __bf16* lonF  = wlonF + (size_t)(b * 8 + xt) * 16384;   // [kt][nf][lane][8]
    const __bf16* Ubase = U_F + (size_t)(b * CP) * 131072 + (size_t)yt * 16384;

    auto stage = [&](int slot, int kt) {
#pragma unroll
        for (int i = 0; i < 6; ++i) {
            const int jf = wave * 6 + i;
            const __bf16* src;
            if (jf < 20) {
                const int jj = jf >> 2;
                const int ch = (jj == 0) ? 0 : (g * 4 + jj);
                src = Ubase + (size_t)ch * 131072
                      + (size_t)(kt * 4 + (jf & 3)) * 512 + lane * 8;
            } else {
                src = lonF + (size_t)(kt * 4 + (jf - 20)) * 512 + lane * 8;
            }
            gload16_lds((const void*)src, (void*)&Ast[slot][jf * 512]);
        }
    };

    stage(0, 0);

    f32x4 acc[5][2][2] = {};
#pragma unroll
    for (int kt = 0; kt < 8; ++kt) {
        const int slot = kt & 1;
        if (kt < 7) {
            stage(slot ^ 1, kt + 1);
            asm volatile("s_waitcnt vmcnt(6)" ::: "memory");   // phase kt landed
        } else {
            asm volatile("s_waitcnt vmcnt(0)" ::: "memory");
        }
        __builtin_amdgcn_s_barrier();
        bf16x8 af[5][2], bfv[2];
#pragma unroll
        for (int j = 0; j < 5; ++j)
#pragma unroll
            for (int mt = 0; mt < 2; ++mt)
                af[j][mt] = *(const bf16x8*)
                    &Ast[slot][((j * 4 + wm * 2 + mt) * 64 + lane) * 8];
#pragma unroll
        for (int nt = 0; nt < 2; ++nt)
            bfv[nt] = *(const bf16x8*)
                &Ast[slot][((20 + wn * 2 + nt) * 64 + lane) * 8];
        asm volatile("s_waitcnt lgkmcnt(0)" ::: "memory");
        __builtin_amdgcn_sched_barrier(0);
#pragma unroll
        for (int j = 0; j < 5; ++j)
#pragma unroll
            for (int mt = 0; mt < 2; ++mt)
#pragma unroll
                for (int nt = 0; nt < 2; ++nt)
                    acc[j][mt][nt] = __builtin_amdgcn_mfma_f32_16x16x32_bf16(
                        af[j][mt], bfv[nt], acc[j][mt][nt], 0, 0, 0);
        __builtin_amdgcn_sched_barrier(0);
        __builtin_amdgcn_s_barrier();   // slot safe to overwrite next phase
    }

    // ---- epilogue: rec from density acc, divide, store ----
    f32x4 rec[2][2];
#pragma unroll
    for (int mt = 0; mt < 2; ++mt)
#pragma unroll
        for (int nt = 0; nt < 2; ++nt) {
            f32x4 c = acc[0][mt][nt], q2;
#pragma unroll
            for (int rr = 0; rr < 4; ++rr)
                q2[rr] = 1.0f / fminf(fmaxf(c[rr], 1e-6f), 1e5f);
            rec[mt][nt] = q2;
        }
    if (g == 0) {
        float* outc = out + (size_t)(b * CP) * (X_ * Y_);
#pragma unroll
        for (int mt = 0; mt < 2; ++mt)
#pragma unroll
            for (int nt = 0; nt < 2; ++nt) {
                int xg = x0 + (wn * 2 + nt) * 16 + lrow;
                int yg = y0 + (wm * 2 + mt) * 16 + lkg * 4;
                *(f32x4*)&outc[(size_t)xg * Y_ + yg] = acc[0][mt][nt];
            }
    }
#pragma unroll
    for (int j = 1; j < 5; ++j) {
        float* outc = out + (size_t)(b * CP + g * 4 + j) * (size_t)(X_ * Y_);
#pragma unroll
        for (int mt = 0; mt < 2; ++mt)
#pragma unroll
            for (int nt = 0; nt < 2; ++nt) {
                int xg = x0 + (wn * 2 + nt) * 16 + lrow;
                int yg = y0 + (wm * 2 + mt) * 16 + lkg * 4;
                f32x4 v = acc[j][mt][nt] * rec[mt][nt];
                *(f32x4*)&outc[(size_t)xg * Y_ + yg] = v;
            }
    }
}

extern "C" void kernel_launch(void* const* d_in, const int* in_sizes, int n_in,
                              void* d_out, int out_size, void* d_ws, size_t ws_size,
                              hipStream_t stream)
{
    const float* xin_lon  = (const float*)d_in[0];
    const float* xin_lat  = (const float*)d_in[1];
    const float* wt       = (const float*)d_in[2];
    const float* xout_lon = (const float*)d_in[3];
    const float* xout_lat = (const float*)d_in[4];
    const float* init_ls  = (const float*)d_in[5];
    float* out = (float*)d_out;

    __bf16* wlonF = (__bf16*)d_ws;
    __bf16* wlatF = wlonF + (size_t)B_ * X_ * W_;
    __bf16* wt33F = wlatF + (size_t)B_ * Y_ * H_;
    __bf16* U_F   = wt33F + (size_t)B_ * CP * W_ * H_;

    // 528 wt33F tile blocks + 256 table blocks
    prep_kernel<<<784, 256, 0, stream>>>(xin_lon, xin_lat, xout_lon, xout_lat,
                                         init_ls, wt, wlonF, wlatF, wt33F);
    gemm_u<<<1056, 256, 0, stream>>>(wt33F, wlatF, U_F);
    stage2_fused<<<1024, 256, 0, stream>>>(wlonF, U_F, out);
}